// Round 10
// baseline (40929.199 us; speedup 1.0000x reference)
//
#include <hip/hip_runtime.h>
#include <stdint.h>

#define N_NODES 10000
#define E_EDGES 640000
#define D_IN    256
#define H_DIM   512
#define KWG     64    // merged-layer workgroups (8 units of each layer per WG)
#define RING    64    // chunk ring depth (steps)

typedef unsigned short ushort_t;
typedef unsigned int   uint32;
typedef unsigned long long u64;

// ---------- bf16 helpers (pre0 internal storage only) ----------
__device__ __forceinline__ float bf2f(ushort_t u) {
  union { uint32 i; float f; } v; v.i = ((uint32)u) << 16; return v.f;
}
__device__ __forceinline__ ushort_t f2bf(float f) {
  union { float f; uint32 i; } v; v.f = f;
  uint32 x = v.i;
  uint32 r = (x + 0x7FFFu + ((x >> 16) & 1u)) >> 16;
  return (ushort_t)r;
}

// ---------- fast gate math ----------
__device__ __forceinline__ float sigmoid_f(float x) {
  return 1.f / (1.f + __expf(-x));
}
__device__ __forceinline__ float tanh_f(float x) {
  x = fminf(10.f, fmaxf(-10.f, x));
  float e2 = __expf(2.f * x);
  return (e2 - 1.f) / (e2 + 1.f);
}

// ---------- fused data+flag 8B chunks: [h fp32 | step+1] via relaxed agent atomics ----------
__device__ __forceinline__ u64 ld_c8(const u64* p) {
  return __hip_atomic_load(p, __ATOMIC_RELAXED, __HIP_MEMORY_SCOPE_AGENT);
}
__device__ __forceinline__ void st_c8(u64* p, float h, int flag) {
  u64 u = ((u64)(uint32)flag << 32) | (u64)__float_as_uint(h);
  __hip_atomic_store(p, u, __ATOMIC_RELAXED, __HIP_MEMORY_SCOPE_AGENT);
}

// ---------- workspace zero (control region only: 57344 B) ----------
__global__ void k_zero(int* p) {
  p[blockIdx.x * 256 + threadIdx.x] = 0;   // 56 blocks -> 14336 words
}

// ---------- edge_index dtype detector ----------
__global__ void k_detect(const int* eb, int* ctrl) {
  int v = eb[2 * (int)threadIdx.x + 1];
  if (v != 0) atomicOr(ctrl, 1);           // 1 => int32, 0 => int64
}

__device__ __forceinline__ int edge_src(const int* eb, int flag, int e) {
  return flag ? eb[e] : eb[2 * e];
}
__device__ __forceinline__ int edge_dst(const int* eb, int flag, int e) {
  return flag ? eb[E_EDGES + e] : eb[2 * (E_EDGES + e)];
}

// ---------- GIN: degree count ----------
__global__ __launch_bounds__(256) void k_count(const int* eb, const int* ctrl, int* deg) {
  int e = blockIdx.x * 256 + threadIdx.x;
  if (e >= E_EDGES) return;
  int flag = ctrl[0];
  atomicAdd(&deg[edge_dst(eb, flag, e)], 1);
}

// ---------- GIN: exclusive prefix sum ----------
__global__ __launch_bounds__(1024) void k_prefix(const int* deg, int* off, int* cursor) {
  __shared__ int sums[1024];
  int tid = threadIdx.x;
  const int PER = 10;
  int base = tid * PER;
  int loc[PER];
  int s = 0;
  for (int i = 0; i < PER; i++) {
    int idx = base + i;
    int v = (idx < N_NODES) ? deg[idx] : 0;
    loc[i] = s; s += v;
  }
  sums[tid] = s;
  __syncthreads();
  for (int d = 1; d < 1024; d <<= 1) {
    int v = (tid >= d) ? sums[tid - d] : 0;
    __syncthreads();
    sums[tid] += v;
    __syncthreads();
  }
  int excl = (tid == 0) ? 0 : sums[tid - 1];
  for (int i = 0; i < PER; i++) {
    int idx = base + i;
    if (idx < N_NODES) { int o = excl + loc[i]; off[idx] = o; cursor[idx] = o; }
  }
  if (tid == 1023) off[N_NODES] = sums[1023];
}

// ---------- GIN: CSR fill ----------
__global__ __launch_bounds__(256) void k_fill(const int* eb, const int* ctrl, int* cursor, int* csr) {
  int e = blockIdx.x * 256 + threadIdx.x;
  if (e >= E_EDGES) return;
  int flag = ctrl[0];
  int d = edge_dst(eb, flag, e);
  int s = edge_src(eb, flag, e);
  int slot = atomicAdd(&cursor[d], 1);
  csr[slot] = s;
}

// ---------- GIN: aggregate ----------
__global__ __launch_bounds__(256) void k_agg(const float* x, const int* off, const int* csr, float* h0) {
  int node = blockIdx.x;
  int f = threadIdx.x;
  float acc = x[(size_t)node * D_IN + f];
  int a = off[node], b = off[node + 1];
  for (int e = a; e < b; e++) {
    int s = csr[e];
    acc += x[(size_t)s * D_IN + f];
  }
  h0[(size_t)node * D_IN + f] = acc;
}

// ---------- fp32 tiled GEMM ----------
template<int KTOT, bool RELU, bool OUTBF16, bool TWOBIAS>
__global__ __launch_bounds__(256) void k_gemm(const float* __restrict__ A,
                                              const float* __restrict__ W,
                                              const float* __restrict__ bias1,
                                              const float* __restrict__ bias2,
                                              void* __restrict__ Cout, int M, int Ncols) {
  __shared__ float As[16][65];
  __shared__ float Ws[16][65];
  int tid = threadIdx.x;
  int tx = tid & 15, ty = tid >> 4;
  int by = blockIdx.x, bn = blockIdx.y;
  int lr  = tid >> 2;
  int lk4 = (tid & 3) * 4;
  float acc[4][4];
  #pragma unroll
  for (int i = 0; i < 4; i++)
    #pragma unroll
    for (int j = 0; j < 4; j++) acc[i][j] = 0.f;

  for (int k0 = 0; k0 < KTOT; k0 += 16) {
    int arow = by * 64 + lr;
    float4 av = make_float4(0.f, 0.f, 0.f, 0.f);
    if (arow < M) av = *(const float4*)(A + (size_t)arow * KTOT + k0 + lk4);
    As[lk4 + 0][lr] = av.x; As[lk4 + 1][lr] = av.y;
    As[lk4 + 2][lr] = av.z; As[lk4 + 3][lr] = av.w;
    float4 wv = *(const float4*)(W + (size_t)(bn * 64 + lr) * KTOT + k0 + lk4);
    Ws[lk4 + 0][lr] = wv.x; Ws[lk4 + 1][lr] = wv.y;
    Ws[lk4 + 2][lr] = wv.z; Ws[lk4 + 3][lr] = wv.w;
    __syncthreads();
    #pragma unroll
    for (int k = 0; k < 16; k++) {
      float a0 = As[k][ty], a1 = As[k][16 + ty], a2 = As[k][32 + ty], a3 = As[k][48 + ty];
      float w0 = Ws[k][tx], w1 = Ws[k][16 + tx], w2 = Ws[k][32 + tx], w3 = Ws[k][48 + tx];
      acc[0][0] += a0 * w0; acc[0][1] += a0 * w1; acc[0][2] += a0 * w2; acc[0][3] += a0 * w3;
      acc[1][0] += a1 * w0; acc[1][1] += a1 * w1; acc[1][2] += a1 * w2; acc[1][3] += a1 * w3;
      acc[2][0] += a2 * w0; acc[2][1] += a2 * w1; acc[2][2] += a2 * w2; acc[2][3] += a2 * w3;
      acc[3][0] += a3 * w0; acc[3][1] += a3 * w1; acc[3][2] += a3 * w2; acc[3][3] += a3 * w3;
    }
    __syncthreads();
  }
  float* Cf = (float*)Cout;
  ushort_t* Cb = (ushort_t*)Cout;
  #pragma unroll
  for (int i = 0; i < 4; i++) {
    int row = by * 64 + 16 * i + ty;
    if (row >= M) continue;
    #pragma unroll
    for (int j = 0; j < 4; j++) {
      int col = bn * 64 + 16 * j + tx;
      float b = bias1[col];
      if (TWOBIAS) b += bias2[col];
      float v = acc[i][j] + b;
      if (RELU) v = fmaxf(v, 0.f);
      if (OUTBF16) Cb[(size_t)row * Ncols + col] = f2bf(v);
      else         Cf[(size_t)row * Ncols + col] = v;
    }
  }
}

// ---------- BatchNorm ----------
__global__ __launch_bounds__(256) void k_bnstats(const float* y2, float* colsum, float* colsumsq) {
  int b = blockIdx.x, tid = threadIdx.x;
  int r0 = b * 64, r1 = min(r0 + 64, N_NODES);
  float s0 = 0, q0 = 0, s1 = 0, q1 = 0;
  for (int r = r0; r < r1; r++) {
    float v0 = y2[(size_t)r * H_DIM + tid];
    float v1 = y2[(size_t)r * H_DIM + tid + 256];
    s0 += v0; q0 += v0 * v0; s1 += v1; q1 += v1 * v1;
  }
  atomicAdd(&colsum[tid], s0);        atomicAdd(&colsumsq[tid], q0);
  atomicAdd(&colsum[tid + 256], s1);  atomicAdd(&colsumsq[tid + 256], q1);
}

__global__ __launch_bounds__(256) void k_bnfin(float* colsum, float* colsumsq,
                                               const float* gamma, const float* beta) {
  int c = blockIdx.x * 256 + threadIdx.x;
  if (c >= H_DIM) return;
  float mean = colsum[c] * (1.f / N_NODES);
  float var  = colsumsq[c] * (1.f / N_NODES) - mean * mean;
  float sc = gamma[c] * rsqrtf(var + 1e-5f);
  float sh = beta[c] - mean * sc;
  colsum[c] = sc; colsumsq[c] = sh;
}

__global__ __launch_bounds__(256) void k_bnapply(float* y2, const float* sc, const float* sh) {
  size_t i = (size_t)blockIdx.x * 256 + threadIdx.x;
  int c = (int)(i & (H_DIM - 1));
  float v = y2[i] * sc[c] + sh[c];
  y2[i] = v > 0.f ? v : 0.f;
}

// ---------- persistent MERGED 2-layer LSTM: 64 WGs, both layers per WG ----------
// WG owns units [8wg, 8wg+8) of BOTH layers. Tick t polls h0(t-1) from hs0c
// slot (t-1) [flag t] and h1(t-2) from hs1c slot (t-2) [flag t-1]  -- r9's
// hang was reading hs1c slot (t-1), whose expected flag never appears.
// One staging barrier, both dots, barrier, wave0 gates l0 while wave1 gates
// l1 in parallel. 10001 ticks, WG skew <=1 tick, no back-pressure needed.
__global__ __launch_bounds__(256, 1) void k_lstm(const ushort_t* pre0, const float* w_hh0,
                                              const float* w_ih1, const float* w_hh1,
                                              const float* b_ih1, const float* b_hh1,
                                              u64* hs0c, u64* hs1c, float* hs1p, float* dout) {
  __shared__ float lds_h[2][1024];     // [h0(t-1) | h1(t-2)], tick-parity double buffer
  __shared__ float lds_d0[32], lds_d1[32];
  __shared__ float lds_pre[2][32];
  int tid = threadIdx.x;
  int wave = tid >> 6, lane = tid & 63;
  int kp = lane & 7;                   // 8 lanes per row
  int r = wave * 8 + (lane >> 3);      // row 0..31 = gate*8 + unit
  int wg = blockIdx.x;
  int u0 = wg * 8;

  float w0r[64], w1r[128];
  {
    // layer0 row r: grow = gate*512 + (u0 + unit); 64-col segment at kp*64
    int grow = (r >> 3) * H_DIM + u0 + (r & 7);
    const float* src = w_hh0 + (size_t)grow * H_DIM + kp * 64;
    #pragma unroll
    for (int i = 0; i < 16; i++) {
      int j0 = ((i + 2 * kp) & 15) * 4;            // bank stagger (2-way max = free)
      float4 v = *(const float4*)(src + j0);
      w0r[4*i+0]=v.x; w0r[4*i+1]=v.y; w0r[4*i+2]=v.z; w0r[4*i+3]=v.w;
    }
  }
  {
    // layer1 row r over concat [h0|h1] (1024): 128-col window at kp*128
    int grow = (r >> 3) * H_DIM + u0 + (r & 7);
    const float* src = (kp < 4) ? (w_ih1 + (size_t)grow * H_DIM + kp * 128)
                                : (w_hh1 + (size_t)grow * H_DIM + (kp - 4) * 128);
    #pragma unroll
    for (int i = 0; i < 32; i++) {
      int j0 = ((i + 5 * kp) & 31) * 4;            // 5*kp distinct mod 8 -> conflict-free
      float4 v = *(const float4*)(src + j0);
      w1r[4*i+0]=v.x; w1r[4*i+1]=v.y; w1r[4*i+2]=v.z; w1r[4*i+3]=v.w;
    }
  }
  float bias1 = 0.f;
  if (wave == 1 && lane < 32) {        // l1 fused bias for row `lane`
    int grow = (lane >> 3) * H_DIM + u0 + (lane & 7);
    bias1 = b_ih1[grow] + b_hh1[grow];
  }
  float pf = 0.f;
  if (tid < 32)                        // pre0 slice for t=0, row tid = gate*8+unit
    pf = bf2f(pre0[(tid >> 3) * H_DIM + u0 + (tid & 7)]);
  float c_reg = 0.f;                   // wave0 lanes<8: l0 cell; wave1 lanes<8: l1 cell

  for (int t = 0; t <= N_NODES; t++) {
    int p = t & 1;
    if (t > 0) {
      // poll h0(t-1): slot t-1, flag t;  h1(t-2): slot t-2, flag t-1
      int slot0 = (t - 1) & (RING - 1);
      int slot1 = (t - 2) & (RING - 1);
      const u64* a0 = hs0c + (size_t)slot0 * 512 + tid;
      const u64* b0 = a0 + 256;
      const u64* a1 = hs1c + (size_t)slot1 * 512 + tid;
      const u64* b1 = a1 + 256;
      bool need1 = (t >= 2);
      u64 ua, ub, va = 0, vb = 0; int guard = 0;
      for (;;) {
        ua = ld_c8(a0); ub = ld_c8(b0);
        bool ok = ((int)(ua >> 32) == t) && ((int)(ub >> 32) == t);
        if (need1) {
          va = ld_c8(a1); vb = ld_c8(b1);
          ok = ok && ((int)(va >> 32) == t - 1) && ((int)(vb >> 32) == t - 1);
        }
        if (ok || ++guard > 50000000) break;
      }
      if (!need1) { va = 0; vb = 0; }
      lds_h[p][tid]        = __uint_as_float((uint32)ua);
      lds_h[p][tid + 256]  = __uint_as_float((uint32)ub);
      lds_h[p][512 + tid]  = __uint_as_float((uint32)va);
      lds_h[p][768 + tid]  = __uint_as_float((uint32)vb);
    }
    if (tid < 32 && t < N_NODES) lds_pre[p][tid] = pf;
    __syncthreads();                                   // A: staging + pre ready
    if (tid < 32 && t + 1 < N_NODES)                   // prefetch next pre0 slice
      pf = bf2f(pre0[(size_t)(t + 1) * 2048 + (tid >> 3) * H_DIM + u0 + (tid & 7)]);
    if (t > 0) {
      if (t < N_NODES) {                               // l0 dot: rows x h0(t-1)
        const float* h = &lds_h[p][kp * 64];
        float d = 0.f;
        #pragma unroll
        for (int i = 0; i < 16; i++) {
          int j0 = ((i + 2 * kp) & 15) * 4;
          float4 x = *(const float4*)(h + j0);
          d += w0r[4*i]*x.x + w0r[4*i+1]*x.y + w0r[4*i+2]*x.z + w0r[4*i+3]*x.w;
        }
        d += __shfl_xor(d, 1, 64);
        d += __shfl_xor(d, 2, 64);
        d += __shfl_xor(d, 4, 64);
        if (kp == 0) lds_d0[r] = d;
      }
      {                                                // l1 dot: rows x [h0(t-1)|h1(t-2)]
        const float* h = &lds_h[p][kp * 128];
        float d = 0.f;
        #pragma unroll
        for (int i = 0; i < 32; i++) {
          int j0 = ((i + 5 * kp) & 31) * 4;
          float4 x = *(const float4*)(h + j0);
          d += w1r[4*i]*x.x + w1r[4*i+1]*x.y + w1r[4*i+2]*x.z + w1r[4*i+3]*x.w;
        }
        d += __shfl_xor(d, 1, 64);
        d += __shfl_xor(d, 2, 64);
        d += __shfl_xor(d, 4, 64);
        if (kp == 0) lds_d1[r] = d;
      }
    }
    __syncthreads();                                   // B: dots ready
    if (wave == 0) {
      if (t < N_NODES) {                               // layer0 gates: h0(t)
        float val = 0.f;
        if (lane < 32) {
          float pre = (t > 0 ? lds_d0[lane] : 0.f) + lds_pre[p][lane];
          val = ((lane >> 3) == 2) ? tanh_f(pre) : sigmoid_f(pre);
        }
        int j = lane & 7;
        float ii = __shfl(val, j, 64);
        float ff = __shfl(val, 8 + j, 64);
        float gg = __shfl(val, 16 + j, 64);
        float oo = __shfl(val, 24 + j, 64);
        if (lane < 8) {
          c_reg = ff * c_reg + ii * gg;
          float hv = oo * tanh_f(c_reg);
          st_c8(hs0c + (size_t)(t & (RING - 1)) * 512 + u0 + lane, hv, t + 1);
          if (t == N_NODES - 1) {
            dout[10000 + u0 + lane] = hv;
            dout[11024 + u0 + lane] = c_reg;
          }
        }
      }
    } else if (wave == 1) {
      if (t >= 1) {                                    // layer1 gates: h1(t-1)
        int s = t - 1;
        float val = 0.f;
        if (lane < 32) {
          float pre = lds_d1[lane] + bias1;
          val = ((lane >> 3) == 2) ? tanh_f(pre) : sigmoid_f(pre);
        }
        int j = lane & 7;
        float ii = __shfl(val, j, 64);
        float ff = __shfl(val, 8 + j, 64);
        float gg = __shfl(val, 16 + j, 64);
        float oo = __shfl(val, 24 + j, 64);
        if (lane < 8) {
          c_reg = ff * c_reg + ii * gg;
          float hv = oo * tanh_f(c_reg);
          st_c8(hs1c + (size_t)(s & (RING - 1)) * 512 + u0 + lane, hv, s + 1);
          hs1p[(size_t)s * H_DIM + u0 + lane] = hv;    // plain store for k_fc
          if (s == N_NODES - 1) {
            dout[10512 + u0 + lane] = hv;
            dout[11536 + u0 + lane] = c_reg;
          }
        }
      }
    }
  }
}

// ---------- fc head ----------
__global__ __launch_bounds__(256) void k_fc(const float* hs1, const float* fc_w,
                                            const float* fc_b, float* dout) {
  int row = blockIdx.x * 4 + (threadIdx.x >> 6);
  int lane = threadIdx.x & 63;
  float acc = 0.f;
  #pragma unroll
  for (int j = 0; j < 8; j++) {
    int c = lane + 64 * j;
    acc += hs1[(size_t)row * H_DIM + c] * fc_w[c];
  }
  for (int d = 32; d; d >>= 1) acc += __shfl_xor(acc, d, 64);
  if (lane == 0) dout[row] = acc + fc_b[0];
}

extern "C" void kernel_launch(void* const* d_in, const int* in_sizes, int n_in,
                              void* d_out, int out_size, void* d_ws, size_t ws_size,
                              hipStream_t stream) {
  const float* x     = (const float*)d_in[0];
  const int*   eb    = (const int*)d_in[1];
  const float* w1    = (const float*)d_in[2];
  const float* b1    = (const float*)d_in[3];
  const float* w2    = (const float*)d_in[4];
  const float* b2    = (const float*)d_in[5];
  const float* gamma = (const float*)d_in[6];
  const float* beta  = (const float*)d_in[7];
  const float* w_ih0 = (const float*)d_in[8];
  const float* w_hh0 = (const float*)d_in[9];
  const float* b_ih0 = (const float*)d_in[10];
  const float* b_hh0 = (const float*)d_in[11];
  const float* w_ih1 = (const float*)d_in[12];
  const float* w_hh1 = (const float*)d_in[13];
  const float* b_ih1 = (const float*)d_in[14];
  const float* b_hh1 = (const float*)d_in[15];
  const float* fc_w  = (const float*)d_in[16];
  const float* fc_b  = (const float*)d_in[17];
  float* dout = (float*)d_out;
  char* ws = (char*)d_ws;

  // ---- workspace layout (bytes); total ~82.5 MB ----
  int*    ctrl     = (int*)(ws + 0);
  float*  colsum   = (float*)(ws + 4096);       // 512 floats
  float*  colsumsq = (float*)(ws + 6144);       // 512 floats
  int*    deg      = (int*)(ws + 8192);         // 10000 ints -> ends 48192 < 57344 (zero region)
  u64*    hs0c     = (u64*)(ws + 65536);        // ring [64][512] 8B chunks = 256 KB
  u64*    hs1c     = (u64*)(ws + 327680);       // ring [64][512] 8B chunks = 256 KB
  float*  y1       = (float*)(ws + 589824);     // [10000,512]; reused as hs1_plain
  float*  y2       = (float*)(ws + 21069824);   // [10000,512]
  float*  h0       = y2;                        // GIN h0 [10000,256] aliases y2
  ushort_t* pre0   = (ushort_t*)(ws + 41549824);// [10000,2048] bf16 -> ends 82509824
  // transient CSR scratch inside pre0's slot (dead before GEMM3 writes pre0):
  int*    off      = (int*)(ws + 41549824);     // 10001 ints
  int*    cursor   = (int*)(ws + 41589828);     // 10000 ints
  int*    csr      = (int*)(ws + 41629828);     // 640000 ints (ends 44189828)
  float*  hs1p     = y1;

  k_zero<<<56, 256, 0, stream>>>((int*)ws);
  k_detect<<<1, 64, 0, stream>>>(eb, ctrl);
  k_count<<<2500, 256, 0, stream>>>(eb, ctrl, deg);
  k_prefix<<<1, 1024, 0, stream>>>(deg, off, cursor);
  k_fill<<<2500, 256, 0, stream>>>(eb, ctrl, cursor, csr);
  k_agg<<<10000, 256, 0, stream>>>(x, off, csr, h0);

  dim3 g1(157, 8);
  k_gemm<256, true,  false, false><<<g1, 256, 0, stream>>>(h0, w1, b1, nullptr, y1, N_NODES, 512);
  dim3 g2(157, 8);
  k_gemm<512, false, false, false><<<g2, 256, 0, stream>>>(y1, w2, b2, nullptr, y2, N_NODES, 512);

  k_bnstats<<<157, 256, 0, stream>>>(y2, colsum, colsumsq);
  k_bnfin<<<2, 256, 0, stream>>>(colsum, colsumsq, gamma, beta);
  k_bnapply<<<20000, 256, 0, stream>>>(y2, colsum, colsumsq);

  dim3 g3(157, 32);
  k_gemm<512, false, true, true><<<g3, 256, 0, stream>>>(y2, w_ih0, b_ih0, b_hh0, pre0, N_NODES, 2048);

  k_lstm<<<KWG, 256, 0, stream>>>(pre0, w_hh0, w_ih1, w_hh1, b_ih1, b_hh1,
                                  hs0c, hs1c, hs1p, dout);
  k_fc<<<2500, 256, 0, stream>>>(hs1p, fc_w, fc_b, dout);
}

// Round 11
// 23878.084 us; speedup vs baseline: 1.7141x; 1.7141x over previous
//
#include <hip/hip_runtime.h>
#include <stdint.h>

#define N_NODES 10000
#define E_EDGES 640000
#define D_IN    256
#define H_DIM   512
#define K0      64    // layer0 workgroups
#define K1      128   // layer1 workgroups
#define RING    64    // chunk ring depth (steps)

typedef unsigned short ushort_t;
typedef unsigned int   uint32;
typedef unsigned long long u64;

// ---------- bf16 helpers (pre0 internal storage only) ----------
__device__ __forceinline__ float bf2f(ushort_t u) {
  union { uint32 i; float f; } v; v.i = ((uint32)u) << 16; return v.f;
}
__device__ __forceinline__ ushort_t f2bf(float f) {
  union { float f; uint32 i; } v; v.f = f;
  uint32 x = v.i;
  uint32 r = (x + 0x7FFFu + ((x >> 16) & 1u)) >> 16;
  return (ushort_t)r;
}

// ---------- fast gate math (rcp-based: off the critical tail) ----------
__device__ __forceinline__ float sigmoid_f(float x) {
  float e = __expf(-x);
  return __builtin_amdgcn_rcpf(1.f + e);
}
__device__ __forceinline__ float tanh_f(float x) {
  x = fminf(10.f, fmaxf(-10.f, x));
  float e2 = __expf(2.f * x);
  return (e2 - 1.f) * __builtin_amdgcn_rcpf(e2 + 1.f);
}

// ---------- fused data+flag 8B chunks: [h fp32 | step+1] via relaxed agent atomics ----------
__device__ __forceinline__ u64 ld_c8(const u64* p) {
  return __hip_atomic_load(p, __ATOMIC_RELAXED, __HIP_MEMORY_SCOPE_AGENT);
}
__device__ __forceinline__ void st_c8(u64* p, float h, int flag) {
  u64 u = ((u64)(uint32)flag << 32) | (u64)__float_as_uint(h);
  __hip_atomic_store(p, u, __ATOMIC_RELAXED, __HIP_MEMORY_SCOPE_AGENT);
}
__device__ __forceinline__ void spin_relaxed(int* p, int target) {
  int guard = 0;
  while (__hip_atomic_load(p, __ATOMIC_RELAXED, __HIP_MEMORY_SCOPE_AGENT) < target) {
    __builtin_amdgcn_s_sleep(1);
    if (++guard > 100000000) break;  // safety valve
  }
  __atomic_signal_fence(__ATOMIC_ACQUIRE);
}

// ---------- workspace zero (control region only: 57344 B) ----------
__global__ void k_zero(int* p) {
  p[blockIdx.x * 256 + threadIdx.x] = 0;   // 56 blocks -> 14336 words
}

// ---------- edge_index dtype detector ----------
__global__ void k_detect(const int* eb, int* ctrl) {
  int v = eb[2 * (int)threadIdx.x + 1];
  if (v != 0) atomicOr(ctrl, 1);           // 1 => int32, 0 => int64
}

__device__ __forceinline__ int edge_src(const int* eb, int flag, int e) {
  return flag ? eb[e] : eb[2 * e];
}
__device__ __forceinline__ int edge_dst(const int* eb, int flag, int e) {
  return flag ? eb[E_EDGES + e] : eb[2 * (E_EDGES + e)];
}

// ---------- GIN: degree count ----------
__global__ __launch_bounds__(256) void k_count(const int* eb, const int* ctrl, int* deg) {
  int e = blockIdx.x * 256 + threadIdx.x;
  if (e >= E_EDGES) return;
  int flag = ctrl[0];
  atomicAdd(&deg[edge_dst(eb, flag, e)], 1);
}

// ---------- GIN: exclusive prefix sum ----------
__global__ __launch_bounds__(1024) void k_prefix(const int* deg, int* off, int* cursor) {
  __shared__ int sums[1024];
  int tid = threadIdx.x;
  const int PER = 10;
  int base = tid * PER;
  int loc[PER];
  int s = 0;
  for (int i = 0; i < PER; i++) {
    int idx = base + i;
    int v = (idx < N_NODES) ? deg[idx] : 0;
    loc[i] = s; s += v;
  }
  sums[tid] = s;
  __syncthreads();
  for (int d = 1; d < 1024; d <<= 1) {
    int v = (tid >= d) ? sums[tid - d] : 0;
    __syncthreads();
    sums[tid] += v;
    __syncthreads();
  }
  int excl = (tid == 0) ? 0 : sums[tid - 1];
  for (int i = 0; i < PER; i++) {
    int idx = base + i;
    if (idx < N_NODES) { int o = excl + loc[i]; off[idx] = o; cursor[idx] = o; }
  }
  if (tid == 1023) off[N_NODES] = sums[1023];
}

// ---------- GIN: CSR fill ----------
__global__ __launch_bounds__(256) void k_fill(const int* eb, const int* ctrl, int* cursor, int* csr) {
  int e = blockIdx.x * 256 + threadIdx.x;
  if (e >= E_EDGES) return;
  int flag = ctrl[0];
  int d = edge_dst(eb, flag, e);
  int s = edge_src(eb, flag, e);
  int slot = atomicAdd(&cursor[d], 1);
  csr[slot] = s;
}

// ---------- GIN: aggregate ----------
__global__ __launch_bounds__(256) void k_agg(const float* x, const int* off, const int* csr, float* h0) {
  int node = blockIdx.x;
  int f = threadIdx.x;
  float acc = x[(size_t)node * D_IN + f];
  int a = off[node], b = off[node + 1];
  for (int e = a; e < b; e++) {
    int s = csr[e];
    acc += x[(size_t)s * D_IN + f];
  }
  h0[(size_t)node * D_IN + f] = acc;
}

// ---------- fp32 tiled GEMM ----------
template<int KTOT, bool RELU, bool OUTBF16, bool TWOBIAS>
__global__ __launch_bounds__(256) void k_gemm(const float* __restrict__ A,
                                              const float* __restrict__ W,
                                              const float* __restrict__ bias1,
                                              const float* __restrict__ bias2,
                                              void* __restrict__ Cout, int M, int Ncols) {
  __shared__ float As[16][65];
  __shared__ float Ws[16][65];
  int tid = threadIdx.x;
  int tx = tid & 15, ty = tid >> 4;
  int by = blockIdx.x, bn = blockIdx.y;
  int lr  = tid >> 2;
  int lk4 = (tid & 3) * 4;
  float acc[4][4];
  #pragma unroll
  for (int i = 0; i < 4; i++)
    #pragma unroll
    for (int j = 0; j < 4; j++) acc[i][j] = 0.f;

  for (int k0 = 0; k0 < KTOT; k0 += 16) {
    int arow = by * 64 + lr;
    float4 av = make_float4(0.f, 0.f, 0.f, 0.f);
    if (arow < M) av = *(const float4*)(A + (size_t)arow * KTOT + k0 + lk4);
    As[lk4 + 0][lr] = av.x; As[lk4 + 1][lr] = av.y;
    As[lk4 + 2][lr] = av.z; As[lk4 + 3][lr] = av.w;
    float4 wv = *(const float4*)(W + (size_t)(bn * 64 + lr) * KTOT + k0 + lk4);
    Ws[lk4 + 0][lr] = wv.x; Ws[lk4 + 1][lr] = wv.y;
    Ws[lk4 + 2][lr] = wv.z; Ws[lk4 + 3][lr] = wv.w;
    __syncthreads();
    #pragma unroll
    for (int k = 0; k < 16; k++) {
      float a0 = As[k][ty], a1 = As[k][16 + ty], a2 = As[k][32 + ty], a3 = As[k][48 + ty];
      float w0 = Ws[k][tx], w1 = Ws[k][16 + tx], w2 = Ws[k][32 + tx], w3 = Ws[k][48 + tx];
      acc[0][0] += a0 * w0; acc[0][1] += a0 * w1; acc[0][2] += a0 * w2; acc[0][3] += a0 * w3;
      acc[1][0] += a1 * w0; acc[1][1] += a1 * w1; acc[1][2] += a1 * w2; acc[1][3] += a1 * w3;
      acc[2][0] += a2 * w0; acc[2][1] += a2 * w1; acc[2][2] += a2 * w2; acc[2][3] += a2 * w3;
      acc[3][0] += a3 * w0; acc[3][1] += a3 * w1; acc[3][2] += a3 * w2; acc[3][3] += a3 * w3;
    }
    __syncthreads();
  }
  float* Cf = (float*)Cout;
  ushort_t* Cb = (ushort_t*)Cout;
  #pragma unroll
  for (int i = 0; i < 4; i++) {
    int row = by * 64 + 16 * i + ty;
    if (row >= M) continue;
    #pragma unroll
    for (int j = 0; j < 4; j++) {
      int col = bn * 64 + 16 * j + tx;
      float b = bias1[col];
      if (TWOBIAS) b += bias2[col];
      float v = acc[i][j] + b;
      if (RELU) v = fmaxf(v, 0.f);
      if (OUTBF16) Cb[(size_t)row * Ncols + col] = f2bf(v);
      else         Cf[(size_t)row * Ncols + col] = v;
    }
  }
}

// ---------- BatchNorm ----------
__global__ __launch_bounds__(256) void k_bnstats(const float* y2, float* colsum, float* colsumsq) {
  int b = blockIdx.x, tid = threadIdx.x;
  int r0 = b * 64, r1 = min(r0 + 64, N_NODES);
  float s0 = 0, q0 = 0, s1 = 0, q1 = 0;
  for (int r = r0; r < r1; r++) {
    float v0 = y2[(size_t)r * H_DIM + tid];
    float v1 = y2[(size_t)r * H_DIM + tid + 256];
    s0 += v0; q0 += v0 * v0; s1 += v1; q1 += v1 * v1;
  }
  atomicAdd(&colsum[tid], s0);        atomicAdd(&colsumsq[tid], q0);
  atomicAdd(&colsum[tid + 256], s1);  atomicAdd(&colsumsq[tid + 256], q1);
}

__global__ __launch_bounds__(256) void k_bnfin(float* colsum, float* colsumsq,
                                               const float* gamma, const float* beta) {
  int c = blockIdx.x * 256 + threadIdx.x;
  if (c >= H_DIM) return;
  float mean = colsum[c] * (1.f / N_NODES);
  float var  = colsumsq[c] * (1.f / N_NODES) - mean * mean;
  float sc = gamma[c] * rsqrtf(var + 1e-5f);
  float sh = beta[c] - mean * sc;
  colsum[c] = sc; colsumsq[c] = sh;
}

__global__ __launch_bounds__(256) void k_bnapply(float* y2, const float* sc, const float* sh) {
  size_t i = (size_t)blockIdx.x * 256 + threadIdx.x;
  int c = (int)(i & (H_DIM - 1));
  float v = y2[i] * sc[c] + sh[c];
  y2[i] = v > 0.f ? v : 0.f;
}

// ---------- persistent 2-layer LSTM scan (r5 structure + micro-opts) ----------
// Transport: fused [h|step+1] 8B chunks in RING-deep rings; poll IS the gather.
// Micro-opts vs r5: adjacent-chunk polling (2tid,2tid+1), hot-spin detect (no
// sleep first 16 iters), l1 split poll (verify h1 once, tight-poll late h0),
// rcp-based gates on the wave0 serial tail.
__global__ __launch_bounds__(256, 1) void k_lstm(const ushort_t* pre0, const float* w_hh0,
                                              const float* w_ih1, const float* w_hh1,
                                              const float* b_ih1, const float* b_hh1,
                                              u64* hs0c, u64* hs1c, float* hs1p,
                                              int* flags1, float* dout) {
  __shared__ float lds_in[2][512];
  __shared__ float lds_dots[32];
  __shared__ float lds_pre[2][32];     // layer0: pre0 slice (double-buffered); layer1: [0]=bias
  int tid = threadIdx.x;
  int wave = tid >> 6, lane = tid & 63;
  int kp = lane & 7;
  int r = wave * 8 + (lane >> 3);
  int wg = blockIdx.x;

  float w_reg[64];
  float c_reg = 0.f;

  if (wg < K0) {
    // ---------------- layer 0: owns units [u0, u0+8); rows = gate*8 + j ----------------
    int u0 = wg * 8;
    {
      int grow = (r >> 3) * H_DIM + u0 + (r & 7);
      const float* src = w_hh0 + (size_t)grow * H_DIM + kp * 64;
      #pragma unroll
      for (int i = 0; i < 16; i++) {
        int j0 = ((i + 2 * kp) & 15) * 4;            // bank stagger
        float4 v = *(const float4*)(src + j0);
        w_reg[4 * i + 0] = v.x; w_reg[4 * i + 1] = v.y;
        w_reg[4 * i + 2] = v.z; w_reg[4 * i + 3] = v.w;
      }
    }
    float pf = 0.f;
    if (tid < 32)
      pf = bf2f(pre0[(tid >> 3) * H_DIM + u0 + (tid & 7)]);   // t = 0 slice

    for (int t = 0; t < N_NODES; t++) {
      int phase = t & 1;
      if (t > 0) {
        // poll h(t-1) chunks (adjacent pair); hot-spin first, sleep later
        const u64* pa = hs0c + (size_t)((t - 1) & (RING - 1)) * 512 + 2 * tid;
        u64 ua, ub; int guard = 0;
        for (;;) {
          ua = ld_c8(pa); ub = ld_c8(pa + 1);
          if ((int)(ua >> 32) == t && (int)(ub >> 32) == t) break;
          if (++guard > 16) __builtin_amdgcn_s_sleep(1);
          if (guard > 100000000) break;
        }
        lds_in[0][2 * tid]     = __uint_as_float((uint32)ua);
        lds_in[0][2 * tid + 1] = __uint_as_float((uint32)ub);
      }
      if (tid < 32) lds_pre[phase][tid] = pf;
      __syncthreads();                                   // A: lds_in + lds_pre ready
      if (tid < 32 && t + 1 < N_NODES)                   // prefetch next pre0 slice
        pf = bf2f(pre0[(size_t)(t + 1) * 2048 + (tid >> 3) * H_DIM + u0 + (tid & 7)]);
      // amortized back-pressure: layer1 read-progress must stay within RING
      if ((t & 31) == 0 && t >= RING && tid < K1)
        spin_relaxed(&flags1[tid * 16], t - 32);
      if (t > 0) {
        const float* hrow = &lds_in[0][kp * 64];
        float dot = 0.f;
        #pragma unroll
        for (int i = 0; i < 16; i++) {
          int j0 = ((i + 2 * kp) & 15) * 4;              // matches weight stagger
          float4 h4 = *(const float4*)(hrow + j0);
          dot += w_reg[4 * i] * h4.x + w_reg[4 * i + 1] * h4.y
               + w_reg[4 * i + 2] * h4.z + w_reg[4 * i + 3] * h4.w;
        }
        dot += __shfl_xor(dot, 1, 64);
        dot += __shfl_xor(dot, 2, 64);
        dot += __shfl_xor(dot, 4, 64);
        if (kp == 0) lds_dots[r] = dot;
      } else if (tid < 32) {
        lds_dots[tid] = 0.f;
      }
      __syncthreads();                                   // B: lds_dots ready
      if (wave == 0) {
        float val = 0.f;
        if (lane < 32) {
          float pre = lds_dots[lane] + lds_pre[phase][lane];
          val = ((lane >> 3) == 2) ? tanh_f(pre) : sigmoid_f(pre);
        }
        int j = lane & 7;
        float ii = __shfl(val, j, 64);
        float ff = __shfl(val, 8 + j, 64);
        float gg = __shfl(val, 16 + j, 64);
        float oo = __shfl(val, 24 + j, 64);
        if (lane < 8) {
          c_reg = ff * c_reg + ii * gg;
          float hv = oo * tanh_f(c_reg);
          st_c8(hs0c + (size_t)(t & (RING - 1)) * 512 + u0 + lane, hv, t + 1);
          if (t == N_NODES - 1) {
            dout[10000 + u0 + lane] = hv;
            dout[11024 + u0 + lane] = c_reg;
          }
        }
      }
      // no tail barrier: next iteration's A covers lds reuse (wave0 arrives last)
    }
  } else {
    // ------- layer 1: owns units [u0, u0+4); rows 0..15 = W_ih1 (g*4+j), 16..31 = W_hh1 -------
    int wg1 = wg - K0;
    int u0 = wg1 * 4;
    int m = r >> 4;                     // wave-uniform: waves 0,1 -> ih; waves 2,3 -> hh
    {
      int gj = r & 15;
      int grow = (gj >> 2) * H_DIM + u0 + (gj & 3);
      const float* src = (m ? w_hh1 : w_ih1) + (size_t)grow * H_DIM + kp * 64;
      #pragma unroll
      for (int i = 0; i < 16; i++) {
        int j0 = ((i + 2 * kp) & 15) * 4;
        float4 v = *(const float4*)(src + j0);
        w_reg[4 * i + 0] = v.x; w_reg[4 * i + 1] = v.y;
        w_reg[4 * i + 2] = v.z; w_reg[4 * i + 3] = v.w;
      }
    }
    if (tid < 16) {
      int g = tid >> 2, j = tid & 3;
      int grow = g * H_DIM + u0 + j;
      lds_pre[0][tid] = b_ih1[grow] + b_hh1[grow];   // fused bias, static
    }
    __syncthreads();

    for (int s = 0; s < N_NODES; s++) {
      {
        // h1(s-1) first (produced a full tick ago -- almost always ready)
        u64 u1a = 0, u1b = 0;
        if (s > 0) {
          const u64* p1 = hs1c + (size_t)((s - 1) & (RING - 1)) * 512 + 2 * tid;
          int guard = 0;
          for (;;) {
            u1a = ld_c8(p1); u1b = ld_c8(p1 + 1);
            if ((int)(u1a >> 32) == s && (int)(u1b >> 32) == s) break;
            if (++guard > 16) __builtin_amdgcn_s_sleep(1);
            if (guard > 100000000) break;
          }
        }
        // tight-poll the late arrival h0(s): 2 loads per iteration
        const u64* p0 = hs0c + (size_t)(s & (RING - 1)) * 512 + 2 * tid;
        u64 u0a, u0b; int guard = 0;
        for (;;) {
          u0a = ld_c8(p0); u0b = ld_c8(p0 + 1);
          if ((int)(u0a >> 32) == s + 1 && (int)(u0b >> 32) == s + 1) break;
          if (++guard > 16) __builtin_amdgcn_s_sleep(1);
          if (guard > 100000000) break;
        }
        lds_in[0][2 * tid]     = __uint_as_float((uint32)u0a);
        lds_in[0][2 * tid + 1] = __uint_as_float((uint32)u0b);
        lds_in[1][2 * tid]     = __uint_as_float((uint32)u1a);
        lds_in[1][2 * tid + 1] = __uint_as_float((uint32)u1b);
      }
      __syncthreads();                                   // A
      if (tid == 0)                                      // read-progress publish
        __hip_atomic_store(&flags1[wg1 * 16], s + 1, __ATOMIC_RELAXED, __HIP_MEMORY_SCOPE_AGENT);
      {
        const float* hrow = &lds_in[m][kp * 64];
        float dot = 0.f;
        #pragma unroll
        for (int i = 0; i < 16; i++) {
          int j0 = ((i + 2 * kp) & 15) * 4;
          float4 h4 = *(const float4*)(hrow + j0);
          dot += w_reg[4 * i] * h4.x + w_reg[4 * i + 1] * h4.y
               + w_reg[4 * i + 2] * h4.z + w_reg[4 * i + 3] * h4.w;
        }
        dot += __shfl_xor(dot, 1, 64);
        dot += __shfl_xor(dot, 2, 64);
        dot += __shfl_xor(dot, 4, 64);
        if (kp == 0) lds_dots[r] = dot;
      }
      __syncthreads();                                   // B
      if (wave == 0) {
        float val = 0.f;
        if (lane < 16) {
          float pre = lds_dots[lane] + lds_dots[16 + lane] + lds_pre[0][lane];
          val = ((lane >> 2) == 2) ? tanh_f(pre) : sigmoid_f(pre);
        }
        int j = lane & 3;
        float ii = __shfl(val, j, 64);
        float ff = __shfl(val, 4 + j, 64);
        float gg = __shfl(val, 8 + j, 64);
        float oo = __shfl(val, 12 + j, 64);
        if (lane < 4) {
          c_reg = ff * c_reg + ii * gg;
          float hv = oo * tanh_f(c_reg);
          st_c8(hs1c + (size_t)(s & (RING - 1)) * 512 + u0 + lane, hv, s + 1);
          hs1p[(size_t)s * H_DIM + u0 + lane] = hv;      // plain store for k_fc
          if (s == N_NODES - 1) {
            dout[10512 + u0 + lane] = hv;
            dout[11536 + u0 + lane] = c_reg;
          }
        }
      }
    }
  }
}

// ---------- fc head ----------
__global__ __launch_bounds__(256) void k_fc(const float* hs1, const float* fc_w,
                                            const float* fc_b, float* dout) {
  int row = blockIdx.x * 4 + (threadIdx.x >> 6);
  int lane = threadIdx.x & 63;
  float acc = 0.f;
  #pragma unroll
  for (int j = 0; j < 8; j++) {
    int c = lane + 64 * j;
    acc += hs1[(size_t)row * H_DIM + c] * fc_w[c];
  }
  for (int d = 32; d; d >>= 1) acc += __shfl_xor(acc, d, 64);
  if (lane == 0) dout[row] = acc + fc_b[0];
}

extern "C" void kernel_launch(void* const* d_in, const int* in_sizes, int n_in,
                              void* d_out, int out_size, void* d_ws, size_t ws_size,
                              hipStream_t stream) {
  const float* x     = (const float*)d_in[0];
  const int*   eb    = (const int*)d_in[1];
  const float* w1    = (const float*)d_in[2];
  const float* b1    = (const float*)d_in[3];
  const float* w2    = (const float*)d_in[4];
  const float* b2    = (const float*)d_in[5];
  const float* gamma = (const float*)d_in[6];
  const float* beta  = (const float*)d_in[7];
  const float* w_ih0 = (const float*)d_in[8];
  const float* w_hh0 = (const float*)d_in[9];
  const float* b_ih0 = (const float*)d_in[10];
  const float* b_hh0 = (const float*)d_in[11];
  const float* w_ih1 = (const float*)d_in[12];
  const float* w_hh1 = (const float*)d_in[13];
  const float* b_ih1 = (const float*)d_in[14];
  const float* b_hh1 = (const float*)d_in[15];
  const float* fc_w  = (const float*)d_in[16];
  const float* fc_b  = (const float*)d_in[17];
  float* dout = (float*)d_out;
  char* ws = (char*)d_ws;

  // ---- workspace layout (bytes); total ~82.5 MB ----
  int*    ctrl     = (int*)(ws + 0);
  int*    flags1   = (int*)(ws + 256);          // 128 * 16 ints
  float*  colsum   = (float*)(ws + 8448);       // 512 floats
  float*  colsumsq = (float*)(ws + 10496);      // 512 floats
  int*    deg      = (int*)(ws + 12544);        // 10000 ints (zero region = first 57344 B)
  u64*    hs0c     = (u64*)(ws + 65536);        // ring [64][512] 8B chunks = 256 KB
  u64*    hs1c     = (u64*)(ws + 327680);       // ring [64][512] 8B chunks = 256 KB
  float*  y1       = (float*)(ws + 589824);     // [10000,512]; reused as hs1_plain
  float*  y2       = (float*)(ws + 21069824);   // [10000,512]
  float*  h0       = y2;                        // GIN h0 [10000,256] aliases y2
  ushort_t* pre0   = (ushort_t*)(ws + 41549824);// [10000,2048] bf16 -> ends 82509824
  // transient CSR scratch inside pre0's slot (dead before GEMM3 writes pre0):
  int*    off      = (int*)(ws + 41549824);     // 10001 ints
  int*    cursor   = (int*)(ws + 41589828);     // 10000 ints
  int*    csr      = (int*)(ws + 41629828);     // 640000 ints (ends 44189828)
  float*  hs1p     = y1;

  k_zero<<<56, 256, 0, stream>>>((int*)ws);
  k_detect<<<1, 64, 0, stream>>>(eb, ctrl);
  k_count<<<2500, 256, 0, stream>>>(eb, ctrl, deg);
  k_prefix<<<1, 1024, 0, stream>>>(deg, off, cursor);
  k_fill<<<2500, 256, 0, stream>>>(eb, ctrl, cursor, csr);
  k_agg<<<10000, 256, 0, stream>>>(x, off, csr, h0);

  dim3 g1(157, 8);
  k_gemm<256, true,  false, false><<<g1, 256, 0, stream>>>(h0, w1, b1, nullptr, y1, N_NODES, 512);
  dim3 g2(157, 8);
  k_gemm<512, false, false, false><<<g2, 256, 0, stream>>>(y1, w2, b2, nullptr, y2, N_NODES, 512);

  k_bnstats<<<157, 256, 0, stream>>>(y2, colsum, colsumsq);
  k_bnfin<<<2, 256, 0, stream>>>(colsum, colsumsq, gamma, beta);
  k_bnapply<<<20000, 256, 0, stream>>>(y2, colsum, colsumsq);

  dim3 g3(157, 32);
  k_gemm<512, false, true, true><<<g3, 256, 0, stream>>>(y2, w_ih0, b_ih0, b_hh0, pre0, N_NODES, 2048);

  k_lstm<<<192, 256, 0, stream>>>(pre0, w_hh0, w_ih1, w_hh1, b_ih1, b_hh1,
                                  hs0c, hs1c, hs1p, flags1, dout);
  k_fc<<<2500, 256, 0, stream>>>(hs1p, fc_w, fc_b, dout);
}